// Round 4
// baseline (206.502 us; speedup 1.0000x reference)
//
#include <hip/hip_runtime.h>
#include <hip/hip_bf16.h>
#include <stdint.h>

#define NB 8
#define LL 4096
#define LQ 2048
#define DD 128

typedef __attribute__((ext_vector_type(8))) short short8;   // bf16x8 MFMA frag
typedef __attribute__((ext_vector_type(4))) short short4v;  // bf16x4
typedef __attribute__((ext_vector_type(4))) float f4;
typedef __attribute__((ext_vector_type(2))) unsigned int u2;

__device__ __forceinline__ short8 pack8(const float* v) {
    __hip_bfloat16 h[8];
    #pragma unroll
    for (int j = 0; j < 8; ++j) h[j] = __float2bfloat16(v[j]);
    return *(short8*)h;
}

// ---------------------------------------------------------------------------
// Kernel A (MFMA): proj = x@W^T + b, q = avgpool2(x)@W^T + b
//   (unchanged — measured ~8 us, at its HBM write floor)
// ---------------------------------------------------------------------------
__global__ __launch_bounds__(256) void projA_kernel(
    const float* __restrict__ x, const float* __restrict__ W,
    const float* __restrict__ bias,
    __hip_bfloat16* __restrict__ proj, __hip_bfloat16* __restrict__ projT,
    __hip_bfloat16* __restrict__ qb, float* __restrict__ qf,
    float* __restrict__ psq, float* __restrict__ qsq)
{
    __shared__ __hip_bfloat16 Wlds[128 * 128];      // 32 KB, XOR-swizzled
    __shared__ __hip_bfloat16 Tt[4][128 * 16];      // 4 KB per-wave transpose tile

    const int tid = threadIdx.x;
    const int lane = tid & 63, w = tid >> 6;
    const int lr = lane & 15, lh = lane >> 4;       // frag row / k-chunk

    #pragma unroll
    for (int k = 0; k < 16; ++k) {
        const int f = k * 1024 + tid * 4;           // flat f32 index
        const int e = f >> 7, col = f & 127;
        f4 v = *(const f4*)&W[f];
        __hip_bfloat16 h[4];
        #pragma unroll
        for (int j = 0; j < 4; ++j) h[j] = __float2bfloat16(v[j]);
        const int byte = e * 256 + (((col * 2)) ^ ((e & 7) << 4));
        *(u2*)((char*)Wlds + byte) = *(u2*)h;
    }
    float bv[8];
    #pragma unroll
    for (int nt = 0; nt < 8; ++nt) bv[nt] = bias[nt * 16 + lr];
    __syncthreads();

    const int tile = blockIdx.x;                    // 768 blocks, 1 tile each
    const int row0 = tile * 64 + w * 16;            // wave's 16 rows
    const bool qmode = tile >= (NB * LL / 64);      // >= 512

    short8 a[4];
    if (!qmode) {
        const float* src = x + (size_t)(row0 + lr) * DD;
        #pragma unroll
        for (int ks = 0; ks < 4; ++ks) {
            float t[8];
            *(f4*)&t[0] = *(const f4*)&src[ks * 32 + lh * 8];
            *(f4*)&t[4] = *(const f4*)&src[ks * 32 + lh * 8 + 4];
            a[ks] = pack8(t);
        }
    } else {
        const int gq = row0 - NB * LL + lr;         // global q row
        const int b = gq >> 11, l = gq & 2047;
        const float* s0 = x + ((size_t)b * LL + 2 * l) * DD;
        #pragma unroll
        for (int ks = 0; ks < 4; ++ks) {
            float t[8];
            f4 u0 = *(const f4*)&s0[ks * 32 + lh * 8];
            f4 u1 = *(const f4*)&s0[ks * 32 + lh * 8 + 4];
            f4 v0 = *(const f4*)&s0[DD + ks * 32 + lh * 8];
            f4 v1 = *(const f4*)&s0[DD + ks * 32 + lh * 8 + 4];
            *(f4*)&t[0] = (u0 + v0) * 0.5f;
            *(f4*)&t[4] = (u1 + v1) * 0.5f;
            a[ks] = pack8(t);
        }
    }

    f4 acc[8] = {};
    #pragma unroll
    for (int nt = 0; nt < 8; ++nt) {
        const int e = nt * 16 + lr;
        #pragma unroll
        for (int ks = 0; ks < 4; ++ks) {
            const int byte = e * 256 + ((ks * 64 + lh * 16) ^ ((lr & 7) << 4));
            short8 bk = *(const short8*)((char*)Wlds + byte);
            acc[nt] = __builtin_amdgcn_mfma_f32_16x16x32_bf16(a[ks], bk, acc[nt], 0, 0, 0);
        }
    }

    __hip_bfloat16 h[8][4];
    f4 rn = {0.f, 0.f, 0.f, 0.f};
    #pragma unroll
    for (int nt = 0; nt < 8; ++nt)
        #pragma unroll
        for (int r = 0; r < 4; ++r) {
            float v = acc[nt][r] + bv[nt];
            acc[nt][r] = v;
            h[nt][r] = __float2bfloat16(v);
            float vb = __bfloat162float(h[nt][r]);
            rn[r] += vb * vb;
        }
    #pragma unroll
    for (int m = 1; m < 16; m <<= 1) {
        #pragma unroll
        for (int r = 0; r < 4; ++r) rn[r] += __shfl_xor(rn[r], m);
    }

    if (!qmode) {
        const int gr = row0;
        #pragma unroll
        for (int nt = 0; nt < 8; ++nt)
            #pragma unroll
            for (int r = 0; r < 4; ++r)
                proj[(size_t)(gr + lh * 4 + r) * DD + nt * 16 + lr] = h[nt][r];
        if (lr == 0) *(f4*)&psq[gr + lh * 4] = rn;
        #pragma unroll
        for (int nt = 0; nt < 8; ++nt) {
            __hip_bfloat16 p[4] = {h[nt][0], h[nt][1], h[nt][2], h[nt][3]};
            *(u2*)((char*)&Tt[w][0] + (nt * 16 + lr) * 32 + lh * 8) = *(u2*)p;
        }
        const int b = gr >> 12, l0 = gr & 4095;
        #pragma unroll
        for (int i = 0; i < 2; ++i) {
            const int e = lane + i * 64;
            short8 t0 = *(const short8*)&Tt[w][e * 16];
            short8 t1 = *(const short8*)&Tt[w][e * 16 + 8];
            __hip_bfloat16* dst = projT + ((size_t)(b * DD + e)) * LL + l0;
            *(short8*)dst = t0;
            *(short8*)(dst + 8) = t1;
        }
    } else {
        const int gq = row0 - NB * LL;
        #pragma unroll
        for (int nt = 0; nt < 8; ++nt)
            #pragma unroll
            for (int r = 0; r < 4; ++r) {
                const size_t idx = (size_t)(gq + lh * 4 + r) * DD + nt * 16 + lr;
                qb[idx] = h[nt][r];
                qf[idx] = acc[nt][r];
            }
        if (lr == 0) *(f4*)&qsq[gq + lh * 4] = rn;
    }
}

// ---------------------------------------------------------------------------
// Kernel B: barrier-free fused similarity, 8 waves / 512 threads.
//   Same swapped-GEMM math as R2 (verified). Each wave owns a private
//   512-key slice (16 iters x 32 keys); main loop has NO barriers.
//   16 waves/CU (vs 8) to hide L2 latency; sqrt via p*rsq(p) (1 trans op).
//   Cross-wave reduce: waves 4-7 park partials in LDS, waves 0-3 add,
//   cooperative final store. 67.6 KB LDS -> 2 blocks/CU.
// ---------------------------------------------------------------------------
__global__ __launch_bounds__(512, 4) void fused_kernel(
    const __hip_bfloat16* __restrict__ proj, const __hip_bfloat16* __restrict__ projT,
    const __hip_bfloat16* __restrict__ qb, const float* __restrict__ psq,
    const float* __restrict__ qsq, float* __restrict__ outk, float* __restrict__ outv)
{
    __shared__ float red[4][32][132];   // 67.6 KB

    const int bid = blockIdx.x;
    const int b = bid & 7;              // XCD-pinned batch
    const int qrow0 = (bid >> 3) * 32;
    const int tid = threadIdx.x;
    const int w = tid >> 6;             // wave 0..7
    const int lane = tid & 63;
    const int lr = lane & 15, lh = lane >> 4;

    const __hip_bfloat16* pjb = proj + (size_t)b * LL * DD;
    const __hip_bfloat16* ptb = projT + (size_t)b * DD * LL;
    const float* psb = psq + b * LL;

    // q fragments (GEMM1 B-operand): lane holds q[qt*16+lr][ks*32+lh*8 ..+7]
    short8 aq[2][4];
    const __hip_bfloat16* qbase = qb + ((size_t)b * LQ + qrow0) * DD;
    #pragma unroll
    for (int qt = 0; qt < 2; ++qt)
        #pragma unroll
        for (int ks = 0; ks < 4; ++ks)
            aq[qt][ks] = *(const short8*)&qbase[(size_t)(qt * 16 + lr) * DD + ks * 32 + lh * 8];
    float qn[2] = { qsq[b * LQ + qrow0 + lr], qsq[b * LQ + qrow0 + 16 + lr] };

    f4 oc[2][8] = {};                   // [qt][dt] partial O accumulators

    const int kbase = w * (LL / 8);     // wave's private 512-key slice
    for (int it = 0; it < (LL / 8) / 32; ++it) {
        const int kk = kbase + it * 32;

        // ---- GEMM1 (swapped): S^T[key][q], keys kk..kk+31 ----
        f4 s[2][2] = {};                // [kt][qt]
        #pragma unroll
        for (int ks = 0; ks < 4; ++ks) {
            short8 ak0 = *(const short8*)&pjb[(size_t)(kk + lr) * DD + ks * 32 + lh * 8];
            short8 ak1 = *(const short8*)&pjb[(size_t)(kk + 16 + lr) * DD + ks * 32 + lh * 8];
            s[0][0] = __builtin_amdgcn_mfma_f32_16x16x32_bf16(ak0, aq[0][ks], s[0][0], 0, 0, 0);
            s[0][1] = __builtin_amdgcn_mfma_f32_16x16x32_bf16(ak0, aq[1][ks], s[0][1], 0, 0, 0);
            s[1][0] = __builtin_amdgcn_mfma_f32_16x16x32_bf16(ak1, aq[0][ks], s[1][0], 0, 0, 0);
            s[1][1] = __builtin_amdgcn_mfma_f32_16x16x32_bf16(ak1, aq[1][ks], s[1][1], 0, 0, 0);
        }

        // ---- transform in-register: lane holds S^T[16kt+4lh+r][16qt+lr] ----
        // dist = p * rsq(p); p clamped to 1e-20 so p=0 -> dist~1e-10 -> exp=1
        f4 pn0 = *(const f4*)&psb[kk + lh * 4];
        f4 pn1 = *(const f4*)&psb[kk + 16 + lh * 4];
        short8 pa[2];
        #pragma unroll
        for (int qt = 0; qt < 2; ++qt) {
            __hip_bfloat16 hh[8];
            #pragma unroll
            for (int r = 0; r < 4; ++r) {
                float p0 = fmaxf(qn[qt] + pn0[r] - 2.0f * s[0][qt][r], 1e-20f);
                float p1 = fmaxf(qn[qt] + pn1[r] - 2.0f * s[1][qt][r], 1e-20f);
                float d0 = p0 * __frsqrt_rn(p0);
                float d1 = p1 * __frsqrt_rn(p1);
                hh[r]     = __float2bfloat16(__expf(-d0));
                hh[4 + r] = __float2bfloat16(__expf(-d1));
            }
            pa[qt] = *(short8*)hh;
        }

        // ---- GEMM2: O += sim @ proj, B from projT at the same key perm ----
        #pragma unroll
        for (int dt = 0; dt < 8; ++dt) {
            const __hip_bfloat16* rowp = ptb + (size_t)(dt * 16 + lr) * LL + kk;
            union { short8 v; short4v h[2]; } u;
            u.h[0] = *(const short4v*)&rowp[lh * 4];        // keys 4lh..4lh+3
            u.h[1] = *(const short4v*)&rowp[16 + lh * 4];   // keys 16+4lh..+3
            oc[0][dt] = __builtin_amdgcn_mfma_f32_16x16x32_bf16(pa[0], u.v, oc[0][dt], 0, 0, 0);
            oc[1][dt] = __builtin_amdgcn_mfma_f32_16x16x32_bf16(pa[1], u.v, oc[1][dt], 0, 0, 0);
        }
    }

    // ---- cross-wave reduce: C layout O[q = qt*16+lh*4+r][d = dt*16+lr] ----
    if (w >= 4) {
        #pragma unroll
        for (int qt = 0; qt < 2; ++qt)
            #pragma unroll
            for (int dt = 0; dt < 8; ++dt)
                #pragma unroll
                for (int r = 0; r < 4; ++r)
                    red[w - 4][qt * 16 + lh * 4 + r][dt * 16 + lr] = oc[qt][dt][r];
    }
    __syncthreads();
    if (w < 4) {
        #pragma unroll
        for (int qt = 0; qt < 2; ++qt)
            #pragma unroll
            for (int dt = 0; dt < 8; ++dt)
                #pragma unroll
                for (int r = 0; r < 4; ++r)
                    red[w][qt * 16 + lh * 4 + r][dt * 16 + lr] += oc[qt][dt][r];
    }
    __syncthreads();

    // ---- final sum of 4 partials + store (512 threads, 4096 f32x2 each... ) ----
    const int row = tid >> 4;            // 0..31
    const int c0 = (tid & 15) * 8;       // 0..120
    float* dk = outk + ((size_t)b * LQ + qrow0 + row) * DD + c0;
    float* dv = outv + ((size_t)b * LQ + qrow0 + row) * DD + c0;
    #pragma unroll
    for (int i = 0; i < 2; ++i) {
        f4 v0 = *(const f4*)&red[0][row][c0 + i * 4];
        f4 v1 = *(const f4*)&red[1][row][c0 + i * 4];
        f4 v2 = *(const f4*)&red[2][row][c0 + i * 4];
        f4 v3 = *(const f4*)&red[3][row][c0 + i * 4];
        f4 vs = (v0 + v1) + (v2 + v3);
        *(f4*)&dk[i * 4] = vs;
        *(f4*)&dv[i * 4] = vs;
    }
}

extern "C" void kernel_launch(void* const* d_in, const int* in_sizes, int n_in,
                              void* d_out, int out_size, void* d_ws, size_t ws_size,
                              hipStream_t stream) {
    const float* x = (const float*)d_in[0];
    const float* W = (const float*)d_in[1];
    const float* bias = (const float*)d_in[2];

    float* out = (float*)d_out;
    const size_t NQ = (size_t)NB * LQ * DD;
    float* qf = out;            // output 0: q
    float* outk = out + NQ;     // output 1: k
    float* outv = out + 2 * NQ; // output 2: v

    char* ws = (char*)d_ws;
    __hip_bfloat16* proj  = (__hip_bfloat16*)ws;                          // 8 MB
    __hip_bfloat16* projT = (__hip_bfloat16*)(ws + 8u * 1024 * 1024);     // 8 MB
    __hip_bfloat16* qb    = (__hip_bfloat16*)(ws + 16u * 1024 * 1024);    // 4 MB
    float* psq            = (float*)(ws + 20u * 1024 * 1024);             // 128 KB
    float* qsq            = (float*)(ws + 20u * 1024 * 1024 + 256u * 1024); // 64 KB

    hipLaunchKernelGGL(projA_kernel, dim3((NB * LL + NB * LQ) / 64), dim3(256), 0, stream,
                       x, W, bias, proj, projT, qb, qf, psq, qsq);
    hipLaunchKernelGGL(fused_kernel, dim3(NB * (LQ / 32)), dim3(512), 0, stream,
                       proj, projT, qb, psq, qsq, outk, outv);
}

// Round 5
// 87.307 us; speedup vs baseline: 2.3652x; 2.3652x over previous
//
#include <hip/hip_runtime.h>
#include <hip/hip_bf16.h>
#include <stdint.h>

#define NB 8
#define LL 4096
#define LQ 2048
#define DD 128

typedef __attribute__((ext_vector_type(8))) short short8;   // bf16x8 MFMA frag
typedef __attribute__((ext_vector_type(4))) short short4v;  // bf16x4
typedef __attribute__((ext_vector_type(4))) float f4;
typedef __attribute__((ext_vector_type(2))) unsigned int u2;

typedef const __attribute__((address_space(1))) unsigned int guint_t;
typedef __attribute__((address_space(3))) unsigned int luint_t;

__device__ __forceinline__ short8 pack8(const float* v) {
    __hip_bfloat16 h[8];
    #pragma unroll
    for (int j = 0; j < 8; ++j) h[j] = __float2bfloat16(v[j]);
    return *(short8*)h;
}

// ---------------------------------------------------------------------------
// Kernel A (MFMA): proj_sw = swizzled(x@W^T + b), q = avgpool2(x)@W^T + b
//   proj_sw rows are 256B with 16B-blocks XOR-permuted by ((row&7)<<4) so the
//   fused kernel's linear global_load_lds yields a bank-conflict-free tile.
// ---------------------------------------------------------------------------
__global__ __launch_bounds__(256) void projA_kernel(
    const float* __restrict__ x, const float* __restrict__ W,
    const float* __restrict__ bias,
    __hip_bfloat16* __restrict__ proj_sw, __hip_bfloat16* __restrict__ projT,
    __hip_bfloat16* __restrict__ qb, float* __restrict__ qf,
    float* __restrict__ psq, float* __restrict__ qsq)
{
    __shared__ __hip_bfloat16 Wlds[128 * 128];      // 32 KB, XOR-swizzled
    __shared__ __hip_bfloat16 Tt[4][128 * 16];      // 4 KB per-wave transpose tile

    const int tid = threadIdx.x;
    const int lane = tid & 63, w = tid >> 6;
    const int lr = lane & 15, lh = lane >> 4;       // frag row / k-chunk

    #pragma unroll
    for (int k = 0; k < 16; ++k) {
        const int f = k * 1024 + tid * 4;           // flat f32 index
        const int e = f >> 7, col = f & 127;
        f4 v = *(const f4*)&W[f];
        __hip_bfloat16 h[4];
        #pragma unroll
        for (int j = 0; j < 4; ++j) h[j] = __float2bfloat16(v[j]);
        const int byte = e * 256 + (((col * 2)) ^ ((e & 7) << 4));
        *(u2*)((char*)Wlds + byte) = *(u2*)h;
    }
    float bv[8];
    #pragma unroll
    for (int nt = 0; nt < 8; ++nt) bv[nt] = bias[nt * 16 + lr];
    __syncthreads();

    const int tile = blockIdx.x;                    // 768 blocks, 1 tile each
    const int row0 = tile * 64 + w * 16;            // wave's 16 rows
    const bool qmode = tile >= (NB * LL / 64);      // >= 512

    short8 a[4];
    if (!qmode) {
        const float* src = x + (size_t)(row0 + lr) * DD;
        #pragma unroll
        for (int ks = 0; ks < 4; ++ks) {
            float t[8];
            *(f4*)&t[0] = *(const f4*)&src[ks * 32 + lh * 8];
            *(f4*)&t[4] = *(const f4*)&src[ks * 32 + lh * 8 + 4];
            a[ks] = pack8(t);
        }
    } else {
        const int gq = row0 - NB * LL + lr;         // global q row
        const int b = gq >> 11, l = gq & 2047;
        const float* s0 = x + ((size_t)b * LL + 2 * l) * DD;
        #pragma unroll
        for (int ks = 0; ks < 4; ++ks) {
            float t[8];
            f4 u0 = *(const f4*)&s0[ks * 32 + lh * 8];
            f4 u1 = *(const f4*)&s0[ks * 32 + lh * 8 + 4];
            f4 v0 = *(const f4*)&s0[DD + ks * 32 + lh * 8];
            f4 v1 = *(const f4*)&s0[DD + ks * 32 + lh * 8 + 4];
            *(f4*)&t[0] = (u0 + v0) * 0.5f;
            *(f4*)&t[4] = (u1 + v1) * 0.5f;
            a[ks] = pack8(t);
        }
    }

    f4 acc[8] = {};
    #pragma unroll
    for (int nt = 0; nt < 8; ++nt) {
        const int e = nt * 16 + lr;
        #pragma unroll
        for (int ks = 0; ks < 4; ++ks) {
            const int byte = e * 256 + ((ks * 64 + lh * 16) ^ ((lr & 7) << 4));
            short8 bk = *(const short8*)((char*)Wlds + byte);
            acc[nt] = __builtin_amdgcn_mfma_f32_16x16x32_bf16(a[ks], bk, acc[nt], 0, 0, 0);
        }
    }

    __hip_bfloat16 h[8][4];
    f4 rn = {0.f, 0.f, 0.f, 0.f};
    #pragma unroll
    for (int nt = 0; nt < 8; ++nt)
        #pragma unroll
        for (int r = 0; r < 4; ++r) {
            float v = acc[nt][r] + bv[nt];
            acc[nt][r] = v;
            h[nt][r] = __float2bfloat16(v);
            float vb = __bfloat162float(h[nt][r]);
            rn[r] += vb * vb;
        }
    #pragma unroll
    for (int m = 1; m < 16; m <<= 1) {
        #pragma unroll
        for (int r = 0; r < 4; ++r) rn[r] += __shfl_xor(rn[r], m);
    }

    if (!qmode) {
        const int gr = row0;
        // swizzled proj write: byte-in-row = (2d) ^ ((row&7)<<4)
        #pragma unroll
        for (int nt = 0; nt < 8; ++nt)
            #pragma unroll
            for (int r = 0; r < 4; ++r) {
                const int row = gr + lh * 4 + r;
                const int byte = (nt * 32 + lr * 2) ^ (((lh * 4 + r) & 7) << 4);
                *(__hip_bfloat16*)((char*)proj_sw + (size_t)row * 256 + byte) = h[nt][r];
            }
        if (lr == 0) *(f4*)&psq[gr + lh * 4] = rn;
        #pragma unroll
        for (int nt = 0; nt < 8; ++nt) {
            __hip_bfloat16 p[4] = {h[nt][0], h[nt][1], h[nt][2], h[nt][3]};
            *(u2*)((char*)&Tt[w][0] + (nt * 16 + lr) * 32 + lh * 8) = *(u2*)p;
        }
        const int b = gr >> 12, l0 = gr & 4095;
        #pragma unroll
        for (int i = 0; i < 2; ++i) {
            const int e = lane + i * 64;
            short8 t0 = *(const short8*)&Tt[w][e * 16];
            short8 t1 = *(const short8*)&Tt[w][e * 16 + 8];
            __hip_bfloat16* dst = projT + ((size_t)(b * DD + e)) * LL + l0;
            *(short8*)dst = t0;
            *(short8*)(dst + 8) = t1;
        }
    } else {
        const int gq = row0 - NB * LL;
        #pragma unroll
        for (int nt = 0; nt < 8; ++nt)
            #pragma unroll
            for (int r = 0; r < 4; ++r) {
                const size_t idx = (size_t)(gq + lh * 4 + r) * DD + nt * 16 + lr;
                qb[idx] = h[nt][r];
                qf[idx] = acc[nt][r];
            }
        if (lr == 0) *(f4*)&qsq[gq + lh * 4] = rn;
    }
}

// ---------------------------------------------------------------------------
// Kernel B: fused similarity, 256-q-row blocks, LDS-staged 32-key tiles.
//   grid = 8 batches x 8 q-tiles x nsplit key-slices; wave w owns 32 q rows.
//   Per tile: proj (8KB, global_load_lds from pre-swizzled global) + projT
//   (8KB reg-staged into 80B-padded rows) double-buffered; swapped-GEMM sim
//   stays lane-local (R2/R3-verified math); one barrier per tile.
//   Each block writes a PARTIAL O for its key slice (no atomics).
// ---------------------------------------------------------------------------
__global__ __launch_bounds__(512, 2) void fused_kernel(
    const __hip_bfloat16* __restrict__ proj_sw, const __hip_bfloat16* __restrict__ projT,
    const __hip_bfloat16* __restrict__ qb, const float* __restrict__ psq,
    const float* __restrict__ qsq,
    float* __restrict__ pp0, float* __restrict__ pp1,
    float* __restrict__ pp2, float* __restrict__ pp3, int keys_per)
{
    __shared__ __hip_bfloat16 pbuf[2][4096];        // 2 x 8 KB proj tile (swizzled)
    __shared__ __hip_bfloat16 tbuf[2][128 * 40];    // 2 x 10 KB projT tile (80B rows)
    __shared__ float psbuf[2048];

    const int bid = blockIdx.x;
    const int b = bid & 7;                          // XCD-pinned batch
    const int qt8 = (bid >> 3) & 7;
    const int ks = bid >> 6;                        // key slice
    const int tid = threadIdx.x;
    const int w = tid >> 6, lane = tid & 63;
    const int lr = lane & 15, lh = lane >> 4;

    const int qrow0 = qt8 * 256 + w * 32;           // wave's 32 q rows
    const int key0 = ks * keys_per;
    const int ntiles = keys_per / 32;

    const char* psw = (const char*)proj_sw + (size_t)b * LL * 256;
    const __hip_bfloat16* ptb = projT + (size_t)b * DD * LL;
    const float* psb = psq + b * LL;

    // psq slice -> LDS
    for (int i = tid; i < keys_per; i += 512) psbuf[i] = psb[key0 + i];

    // q fragments (GEMM1 B-operand) + norms
    short8 aq[2][4];
    const __hip_bfloat16* qbase = qb + ((size_t)b * LQ + qrow0) * DD;
    #pragma unroll
    for (int qt = 0; qt < 2; ++qt)
        #pragma unroll
        for (int kss = 0; kss < 4; ++kss)
            aq[qt][kss] = *(const short8*)&qbase[(size_t)(qt * 16 + lr) * DD + kss * 32 + lh * 8];
    float qn[2] = { qsq[b * LQ + qrow0 + lr], qsq[b * LQ + qrow0 + 16 + lr] };

    // staging thread mapping for projT tile: thread -> (d, 16B segment)
    const int sd = tid >> 2, ss = tid & 3;

    // ---- prologue: stage tile 0 into buffer 0 ----
    __builtin_amdgcn_global_load_lds(
        (guint_t*)(psw + (size_t)key0 * 256 + w * 1024 + lane * 16),
        (luint_t*)&pbuf[0][w * 512], 16, 0, 0);
    {
        short8 t0 = *(const short8*)(ptb + (size_t)sd * LL + key0 + ss * 8);
        *(short8*)((char*)tbuf[0] + sd * 80 + ss * 16) = t0;
    }
    __syncthreads();

    f4 oc[2][8] = {};                               // [qt][dt]
    int p = 0;

    for (int t = 0; t < ntiles; ++t) {
        // ---- issue next tile's staging (T14: issue-early, write-late) ----
        short8 tnext;
        if (t + 1 < ntiles) {
            __builtin_amdgcn_global_load_lds(
                (guint_t*)(psw + (size_t)(key0 + (t + 1) * 32) * 256 + w * 1024 + lane * 16),
                (luint_t*)&pbuf[p ^ 1][w * 512], 16, 0, 0);
            tnext = *(const short8*)(ptb + (size_t)sd * LL + key0 + (t + 1) * 32 + ss * 8);
        }

        // ---- GEMM1 (swapped): S^T[key][q] from LDS proj tile ----
        f4 s[2][2] = {};                            // [kt][qt]
        #pragma unroll
        for (int kss = 0; kss < 4; ++kss) {
            const int off = kss * 64 + lh * 16;
            short8 ak0 = *(const short8*)((char*)pbuf[p] + lr * 256 + (off ^ ((lr & 7) << 4)));
            short8 ak1 = *(const short8*)((char*)pbuf[p] + (16 + lr) * 256 + (off ^ ((lr & 7) << 4)));
            s[0][0] = __builtin_amdgcn_mfma_f32_16x16x32_bf16(ak0, aq[0][kss], s[0][0], 0, 0, 0);
            s[0][1] = __builtin_amdgcn_mfma_f32_16x16x32_bf16(ak0, aq[1][kss], s[0][1], 0, 0, 0);
            s[1][0] = __builtin_amdgcn_mfma_f32_16x16x32_bf16(ak1, aq[0][kss], s[1][0], 0, 0, 0);
            s[1][1] = __builtin_amdgcn_mfma_f32_16x16x32_bf16(ak1, aq[1][kss], s[1][1], 0, 0, 0);
        }

        // ---- transform: lane holds S^T[t*32 + 16kt + 4lh + r][16qt + lr] ----
        f4 pn0 = *(const f4*)&psbuf[t * 32 + lh * 4];
        f4 pn1 = *(const f4*)&psbuf[t * 32 + 16 + lh * 4];
        short8 pa[2];
        #pragma unroll
        for (int qt = 0; qt < 2; ++qt) {
            __hip_bfloat16 hh[8];
            #pragma unroll
            for (int r = 0; r < 4; ++r) {
                float p0 = fmaxf(qn[qt] + pn0[r] - 2.0f * s[0][qt][r], 1e-20f);
                float p1 = fmaxf(qn[qt] + pn1[r] - 2.0f * s[1][qt][r], 1e-20f);
                float d0 = p0 * __frsqrt_rn(p0);
                float d1 = p1 * __frsqrt_rn(p1);
                hh[r]     = __float2bfloat16(__expf(-d0));
                hh[4 + r] = __float2bfloat16(__expf(-d1));
            }
            pa[qt] = *(short8*)hh;
        }

        // ---- GEMM2: O += sim @ proj, B-frags from LDS projT tile ----
        #pragma unroll
        for (int dt = 0; dt < 8; ++dt) {
            const char* rowp = (const char*)tbuf[p] + (dt * 16 + lr) * 80;
            union { short8 v; short4v h[2]; } u;
            u.h[0] = *(const short4v*)(rowp + lh * 8);        // keys 4lh..+3
            u.h[1] = *(const short4v*)(rowp + 32 + lh * 8);   // keys 16+4lh..+3
            oc[0][dt] = __builtin_amdgcn_mfma_f32_16x16x32_bf16(pa[0], u.v, oc[0][dt], 0, 0, 0);
            oc[1][dt] = __builtin_amdgcn_mfma_f32_16x16x32_bf16(pa[1], u.v, oc[1][dt], 0, 0, 0);
        }

        // ---- write-late half of projT staging, then the tile barrier ----
        if (t + 1 < ntiles)
            *(short8*)((char*)tbuf[p ^ 1] + sd * 80 + ss * 16) = tnext;
        __syncthreads();
        p ^= 1;
    }

    // ---- partial O store: O[q = qrow0 + qt*16 + lh*4 + r][d = dt*16 + lr] ----
    float* pb = (ks == 0) ? pp0 : (ks == 1) ? pp1 : (ks == 2) ? pp2 : pp3;
    #pragma unroll
    for (int qt = 0; qt < 2; ++qt)
        #pragma unroll
        for (int dt = 0; dt < 8; ++dt)
            #pragma unroll
            for (int r = 0; r < 4; ++r)
                pb[((size_t)b * LQ + qrow0 + qt * 16 + lh * 4 + r) * DD + dt * 16 + lr] = oc[qt][dt][r];
}

// ---------------------------------------------------------------------------
// Reduce: outk = outv = sum of nsplit partials (p0/p1 alias outk/outv).
// ---------------------------------------------------------------------------
__global__ __launch_bounds__(256) void reduce_kernel(
    const float* __restrict__ p0, const float* __restrict__ p1,
    const float* __restrict__ p2, const float* __restrict__ p3,
    float* __restrict__ outk, float* __restrict__ outv, int nsplit)
{
    const int b = blockIdx.x & 7;
    const size_t j = (size_t)b * (LQ * DD) + ((size_t)(blockIdx.x >> 3) * 256 + threadIdx.x) * 4;
    f4 v = *(const f4*)&p0[j] + *(const f4*)&p1[j];
    if (nsplit == 4) v += *(const f4*)&p2[j] + *(const f4*)&p3[j];
    *(f4*)&outk[j] = v;
    *(f4*)&outv[j] = v;
}

extern "C" void kernel_launch(void* const* d_in, const int* in_sizes, int n_in,
                              void* d_out, int out_size, void* d_ws, size_t ws_size,
                              hipStream_t stream) {
    const float* x = (const float*)d_in[0];
    const float* W = (const float*)d_in[1];
    const float* bias = (const float*)d_in[2];

    float* out = (float*)d_out;
    const size_t NQ = (size_t)NB * LQ * DD;
    float* qf = out;            // output 0: q
    float* outk = out + NQ;     // output 1: k
    float* outv = out + 2 * NQ; // output 2: v

    char* ws = (char*)d_ws;
    __hip_bfloat16* proj  = (__hip_bfloat16*)ws;                          // 8 MB (swizzled)
    __hip_bfloat16* projT = (__hip_bfloat16*)(ws + 8u * 1024 * 1024);     // 8 MB
    __hip_bfloat16* qb    = (__hip_bfloat16*)(ws + 16u * 1024 * 1024);    // 4 MB
    float* psq            = (float*)(ws + 20u * 1024 * 1024);             // 128 KB
    float* qsq            = (float*)(ws + 20u * 1024 * 1024 + 256u * 1024); // 64 KB
    float* pw2            = (float*)(ws + 24u * 1024 * 1024);             // 8 MB partial
    float* pw3            = (float*)(ws + 32u * 1024 * 1024);             // 8 MB partial

    const int nsplit = (ws_size >= (40ull << 20)) ? 4 : 2;
    const int keys_per = LL / nsplit;

    hipLaunchKernelGGL(projA_kernel, dim3((NB * LL + NB * LQ) / 64), dim3(256), 0, stream,
                       x, W, bias, proj, projT, qb, qf, psq, qsq);
    hipLaunchKernelGGL(fused_kernel, dim3(64 * nsplit), dim3(512), 0, stream,
                       proj, projT, qb, psq, qsq, outk, outv, pw2, pw3, keys_per);
    hipLaunchKernelGGL(reduce_kernel, dim3(2048), dim3(256), 0, stream,
                       outk, outv, pw2, pw3, outk, outv, nsplit);
}

// Round 6
// 79.887 us; speedup vs baseline: 2.5849x; 1.0929x over previous
//
#include <hip/hip_runtime.h>
#include <hip/hip_bf16.h>
#include <stdint.h>

#define NB 8
#define LL 4096
#define LQ 2048
#define DD 128

typedef __attribute__((ext_vector_type(8))) short short8;   // bf16x8 MFMA frag
typedef __attribute__((ext_vector_type(4))) short short4v;  // bf16x4
typedef __attribute__((ext_vector_type(4))) float f4;
typedef __attribute__((ext_vector_type(2))) unsigned int u2;

typedef const __attribute__((address_space(1))) unsigned int guint_t;
typedef __attribute__((address_space(3))) unsigned int luint_t;

__device__ __forceinline__ short8 pack8(const float* v) {
    __hip_bfloat16 h[8];
    #pragma unroll
    for (int j = 0; j < 8; ++j) h[j] = __float2bfloat16(v[j]);
    return *(short8*)h;
}

// ---------------------------------------------------------------------------
// Kernel A (MFMA): proj_sw = swizzled(x@W^T + b), q = avgpool2(x)@W^T + b
//   (unchanged — ~8 us, HBM write floor)
// ---------------------------------------------------------------------------
__global__ __launch_bounds__(256) void projA_kernel(
    const float* __restrict__ x, const float* __restrict__ W,
    const float* __restrict__ bias,
    __hip_bfloat16* __restrict__ proj_sw, __hip_bfloat16* __restrict__ projT,
    __hip_bfloat16* __restrict__ qb, float* __restrict__ qf,
    float* __restrict__ psq, float* __restrict__ qsq)
{
    __shared__ __hip_bfloat16 Wlds[128 * 128];      // 32 KB, XOR-swizzled
    __shared__ __hip_bfloat16 Tt[4][128 * 16];      // 4 KB per-wave transpose tile

    const int tid = threadIdx.x;
    const int lane = tid & 63, w = tid >> 6;
    const int lr = lane & 15, lh = lane >> 4;       // frag row / k-chunk

    #pragma unroll
    for (int k = 0; k < 16; ++k) {
        const int f = k * 1024 + tid * 4;           // flat f32 index
        const int e = f >> 7, col = f & 127;
        f4 v = *(const f4*)&W[f];
        __hip_bfloat16 h[4];
        #pragma unroll
        for (int j = 0; j < 4; ++j) h[j] = __float2bfloat16(v[j]);
        const int byte = e * 256 + (((col * 2)) ^ ((e & 7) << 4));
        *(u2*)((char*)Wlds + byte) = *(u2*)h;
    }
    float bv[8];
    #pragma unroll
    for (int nt = 0; nt < 8; ++nt) bv[nt] = bias[nt * 16 + lr];
    __syncthreads();

    const int tile = blockIdx.x;                    // 768 blocks, 1 tile each
    const int row0 = tile * 64 + w * 16;            // wave's 16 rows
    const bool qmode = tile >= (NB * LL / 64);      // >= 512

    short8 a[4];
    if (!qmode) {
        const float* src = x + (size_t)(row0 + lr) * DD;
        #pragma unroll
        for (int ks = 0; ks < 4; ++ks) {
            float t[8];
            *(f4*)&t[0] = *(const f4*)&src[ks * 32 + lh * 8];
            *(f4*)&t[4] = *(const f4*)&src[ks * 32 + lh * 8 + 4];
            a[ks] = pack8(t);
        }
    } else {
        const int gq = row0 - NB * LL + lr;         // global q row
        const int b = gq >> 11, l = gq & 2047;
        const float* s0 = x + ((size_t)b * LL + 2 * l) * DD;
        #pragma unroll
        for (int ks = 0; ks < 4; ++ks) {
            float t[8];
            f4 u0 = *(const f4*)&s0[ks * 32 + lh * 8];
            f4 u1 = *(const f4*)&s0[ks * 32 + lh * 8 + 4];
            f4 v0 = *(const f4*)&s0[DD + ks * 32 + lh * 8];
            f4 v1 = *(const f4*)&s0[DD + ks * 32 + lh * 8 + 4];
            *(f4*)&t[0] = (u0 + v0) * 0.5f;
            *(f4*)&t[4] = (u1 + v1) * 0.5f;
            a[ks] = pack8(t);
        }
    }

    f4 acc[8] = {};
    #pragma unroll
    for (int nt = 0; nt < 8; ++nt) {
        const int e = nt * 16 + lr;
        #pragma unroll
        for (int ks = 0; ks < 4; ++ks) {
            const int byte = e * 256 + ((ks * 64 + lh * 16) ^ ((lr & 7) << 4));
            short8 bk = *(const short8*)((char*)Wlds + byte);
            acc[nt] = __builtin_amdgcn_mfma_f32_16x16x32_bf16(a[ks], bk, acc[nt], 0, 0, 0);
        }
    }

    __hip_bfloat16 h[8][4];
    f4 rn = {0.f, 0.f, 0.f, 0.f};
    #pragma unroll
    for (int nt = 0; nt < 8; ++nt)
        #pragma unroll
        for (int r = 0; r < 4; ++r) {
            float v = acc[nt][r] + bv[nt];
            acc[nt][r] = v;
            h[nt][r] = __float2bfloat16(v);
            float vb = __bfloat162float(h[nt][r]);
            rn[r] += vb * vb;
        }
    #pragma unroll
    for (int m = 1; m < 16; m <<= 1) {
        #pragma unroll
        for (int r = 0; r < 4; ++r) rn[r] += __shfl_xor(rn[r], m);
    }

    if (!qmode) {
        const int gr = row0;
        // swizzled proj write: byte-in-row = (2d) ^ ((row&7)<<4)
        #pragma unroll
        for (int nt = 0; nt < 8; ++nt)
            #pragma unroll
            for (int r = 0; r < 4; ++r) {
                const int row = gr + lh * 4 + r;
                const int byte = (nt * 32 + lr * 2) ^ (((lh * 4 + r) & 7) << 4);
                *(__hip_bfloat16*)((char*)proj_sw + (size_t)row * 256 + byte) = h[nt][r];
            }
        if (lr == 0) *(f4*)&psq[gr + lh * 4] = rn;
        #pragma unroll
        for (int nt = 0; nt < 8; ++nt) {
            __hip_bfloat16 p[4] = {h[nt][0], h[nt][1], h[nt][2], h[nt][3]};
            *(u2*)((char*)&Tt[w][0] + (nt * 16 + lr) * 32 + lh * 8) = *(u2*)p;
        }
        const int b = gr >> 12, l0 = gr & 4095;
        #pragma unroll
        for (int i = 0; i < 2; ++i) {
            const int e = lane + i * 64;
            short8 t0 = *(const short8*)&Tt[w][e * 16];
            short8 t1 = *(const short8*)&Tt[w][e * 16 + 8];
            __hip_bfloat16* dst = projT + ((size_t)(b * DD + e)) * LL + l0;
            *(short8*)dst = t0;
            *(short8*)(dst + 8) = t1;
        }
    } else {
        const int gq = row0 - NB * LL;
        #pragma unroll
        for (int nt = 0; nt < 8; ++nt)
            #pragma unroll
            for (int r = 0; r < 4; ++r) {
                const size_t idx = (size_t)(gq + lh * 4 + r) * DD + nt * 16 + lr;
                qb[idx] = h[nt][r];
                qf[idx] = acc[nt][r];
            }
        if (lr == 0) *(f4*)&qsq[gq + lh * 4] = rn;
    }
}

// ---------------------------------------------------------------------------
// Kernel B: fused similarity, 128-q-row blocks (wave = 16 rows), LDS-staged
//   32-key tiles. grid = 8b x 16qt x nsplit -> 512 blocks = 2/CU (independent
//   barriers fill each other's drain). tbuf rows 72B (18-bank stride: all 16
//   lr rows distinct banks). Swapped-GEMM sim math identical to R2-R4.
// ---------------------------------------------------------------------------
__global__ __launch_bounds__(512, 4) void fused_kernel(
    const __hip_bfloat16* __restrict__ proj_sw, const __hip_bfloat16* __restrict__ projT,
    const __hip_bfloat16* __restrict__ qb, const float* __restrict__ psq,
    const float* __restrict__ qsq,
    float* __restrict__ pp0, float* __restrict__ pp1,
    float* __restrict__ pp2, float* __restrict__ pp3, int keys_per)
{
    __shared__ __hip_bfloat16 pbuf[2][4096];        // 2 x 8 KB proj tile (swizzled)
    __shared__ __hip_bfloat16 tbuf[2][128 * 36];    // 2 x 9 KB projT tile (72B rows)
    __shared__ float psbuf[2048];                   // up to 8 KB psq slice

    const int bid = blockIdx.x;
    const int b = bid & 7;                          // XCD-pinned batch
    const int qt16 = (bid >> 3) & 15;
    const int ks = bid >> 7;                        // key slice
    const int tid = threadIdx.x;
    const int w = tid >> 6, lane = tid & 63;
    const int lr = lane & 15, lh = lane >> 4;

    const int qrow0 = qt16 * 128 + w * 16;          // wave's 16 q rows
    const int key0 = ks * keys_per;
    const int ntiles = keys_per / 32;

    const char* psw = (const char*)proj_sw + (size_t)b * LL * 256;
    const __hip_bfloat16* ptb = projT + (size_t)b * DD * LL;
    const float* psb = psq + b * LL;

    // psq slice -> LDS
    for (int i = tid; i < keys_per; i += 512) psbuf[i] = psb[key0 + i];

    // q fragments (GEMM1 B-operand) + norms
    short8 aq[4];
    const __hip_bfloat16* qbase = qb + ((size_t)b * LQ + qrow0) * DD;
    #pragma unroll
    for (int kss = 0; kss < 4; ++kss)
        aq[kss] = *(const short8*)&qbase[(size_t)lr * DD + kss * 32 + lh * 8];
    const float qn = qsq[b * LQ + qrow0 + lr];

    // staging thread mapping for projT tile: thread -> (d, 16B segment)
    const int sd = tid >> 2, ss = tid & 3;

    // ---- prologue: stage tile 0 into buffer 0 ----
    __builtin_amdgcn_global_load_lds(
        (guint_t*)(psw + (size_t)key0 * 256 + w * 1024 + lane * 16),
        (luint_t*)&pbuf[0][w * 512], 16, 0, 0);
    {
        short8 t0 = *(const short8*)(ptb + (size_t)sd * LL + key0 + ss * 8);
        *(short8*)((char*)tbuf[0] + sd * 72 + ss * 16) = t0;
    }
    __syncthreads();

    f4 oc[8] = {};                                  // [dt]
    int p = 0;

    for (int t = 0; t < ntiles; ++t) {
        // ---- issue next tile's staging (T14: issue-early, write-late) ----
        short8 tnext;
        if (t + 1 < ntiles) {
            __builtin_amdgcn_global_load_lds(
                (guint_t*)(psw + (size_t)(key0 + (t + 1) * 32) * 256 + w * 1024 + lane * 16),
                (luint_t*)&pbuf[p ^ 1][w * 512], 16, 0, 0);
            tnext = *(const short8*)(ptb + (size_t)sd * LL + key0 + (t + 1) * 32 + ss * 8);
        }

        // ---- GEMM1 (swapped): S^T[key][q] from LDS proj tile ----
        f4 s[2] = {};                               // [kt]
        #pragma unroll
        for (int kss = 0; kss < 4; ++kss) {
            const int off = kss * 64 + lh * 16;
            short8 ak0 = *(const short8*)((char*)pbuf[p] + lr * 256 + (off ^ ((lr & 7) << 4)));
            short8 ak1 = *(const short8*)((char*)pbuf[p] + (16 + lr) * 256 + (off ^ ((lr & 7) << 4)));
            s[0] = __builtin_amdgcn_mfma_f32_16x16x32_bf16(ak0, aq[kss], s[0], 0, 0, 0);
            s[1] = __builtin_amdgcn_mfma_f32_16x16x32_bf16(ak1, aq[kss], s[1], 0, 0, 0);
        }

        // ---- transform: lane holds S^T[t*32 + 16kt + 4lh + r][q=lr] ----
        f4 pn0 = *(const f4*)&psbuf[t * 32 + lh * 4];
        f4 pn1 = *(const f4*)&psbuf[t * 32 + 16 + lh * 4];
        short8 pa;
        {
            __hip_bfloat16 hh[8];
            #pragma unroll
            for (int r = 0; r < 4; ++r) {
                float p0 = fmaxf(qn + pn0[r] - 2.0f * s[0][r], 1e-20f);
                float p1 = fmaxf(qn + pn1[r] - 2.0f * s[1][r], 1e-20f);
                float d0 = p0 * __frsqrt_rn(p0);
                float d1 = p1 * __frsqrt_rn(p1);
                hh[r]     = __float2bfloat16(__expf(-d0));
                hh[4 + r] = __float2bfloat16(__expf(-d1));
            }
            pa = *(short8*)hh;
        }

        // ---- GEMM2: O += sim @ proj, B-frags from LDS projT tile ----
        #pragma unroll
        for (int dt = 0; dt < 8; ++dt) {
            const char* rowp = (const char*)tbuf[p] + (dt * 16 + lr) * 72;
            union { short8 v; short4v h[2]; } u;
            u.h[0] = *(const short4v*)(rowp + lh * 8);        // keys 4lh..+3
            u.h[1] = *(const short4v*)(rowp + 32 + lh * 8);   // keys 16+4lh..+3
            oc[dt] = __builtin_amdgcn_mfma_f32_16x16x32_bf16(pa, u.v, oc[dt], 0, 0, 0);
        }

        // ---- write-late half of projT staging, then the tile barrier ----
        if (t + 1 < ntiles)
            *(short8*)((char*)tbuf[p ^ 1] + sd * 72 + ss * 16) = tnext;
        __syncthreads();
        p ^= 1;
    }

    // ---- partial O store: O[q = qrow0 + lh*4 + r][d = dt*16 + lr] ----
    float* pb = (ks == 0) ? pp0 : (ks == 1) ? pp1 : (ks == 2) ? pp2 : pp3;
    #pragma unroll
    for (int dt = 0; dt < 8; ++dt)
        #pragma unroll
        for (int r = 0; r < 4; ++r)
            pb[((size_t)b * LQ + qrow0 + lh * 4 + r) * DD + dt * 16 + lr] = oc[dt][r];
}

// ---------------------------------------------------------------------------
// Reduce: outk = outv = sum of nsplit partials (p0/p1 alias outk/outv).
// ---------------------------------------------------------------------------
__global__ __launch_bounds__(256) void reduce_kernel(
    const float* __restrict__ p0, const float* __restrict__ p1,
    const float* __restrict__ p2, const float* __restrict__ p3,
    float* __restrict__ outk, float* __restrict__ outv, int nsplit)
{
    const int b = blockIdx.x & 7;
    const size_t j = (size_t)b * (LQ * DD) + ((size_t)(blockIdx.x >> 3) * 256 + threadIdx.x) * 4;
    f4 v = *(const f4*)&p0[j] + *(const f4*)&p1[j];
    if (nsplit == 4) v += *(const f4*)&p2[j] + *(const f4*)&p3[j];
    *(f4*)&outk[j] = v;
    *(f4*)&outv[j] = v;
}

extern "C" void kernel_launch(void* const* d_in, const int* in_sizes, int n_in,
                              void* d_out, int out_size, void* d_ws, size_t ws_size,
                              hipStream_t stream) {
    const float* x = (const float*)d_in[0];
    const float* W = (const float*)d_in[1];
    const float* bias = (const float*)d_in[2];

    float* out = (float*)d_out;
    const size_t NQ = (size_t)NB * LQ * DD;
    float* qf = out;            // output 0: q
    float* outk = out + NQ;     // output 1: k
    float* outv = out + 2 * NQ; // output 2: v

    char* ws = (char*)d_ws;
    __hip_bfloat16* proj  = (__hip_bfloat16*)ws;                          // 8 MB (swizzled)
    __hip_bfloat16* projT = (__hip_bfloat16*)(ws + 8u * 1024 * 1024);     // 8 MB
    __hip_bfloat16* qb    = (__hip_bfloat16*)(ws + 16u * 1024 * 1024);    // 4 MB
    float* psq            = (float*)(ws + 20u * 1024 * 1024);             // 128 KB
    float* qsq            = (float*)(ws + 20u * 1024 * 1024 + 256u * 1024); // 64 KB
    float* pw2            = (float*)(ws + 24u * 1024 * 1024);             // 8 MB partial
    float* pw3            = (float*)(ws + 32u * 1024 * 1024);             // 8 MB partial

    const int nsplit = (ws_size >= (40ull << 20)) ? 4 : 2;
    const int keys_per = LL / nsplit;

    hipLaunchKernelGGL(projA_kernel, dim3((NB * LL + NB * LQ) / 64), dim3(256), 0, stream,
                       x, W, bias, proj, projT, qb, qf, psq, qsq);
    hipLaunchKernelGGL(fused_kernel, dim3(128 * nsplit), dim3(512), 0, stream,
                       proj, projT, qb, psq, qsq, outk, outv, pw2, pw3, keys_per);
    hipLaunchKernelGGL(reduce_kernel, dim3(2048), dim3(256), 0, stream,
                       outk, outv, pw2, pw3, outk, outv, nsplit);
}

// Round 7
// 78.745 us; speedup vs baseline: 2.6224x; 1.0145x over previous
//
#include <hip/hip_runtime.h>
#include <hip/hip_bf16.h>
#include <stdint.h>

#define NB 8
#define LL 4096
#define LQ 2048
#define DD 128

typedef __attribute__((ext_vector_type(8))) short short8;   // bf16x8 MFMA frag
typedef __attribute__((ext_vector_type(4))) short short4v;  // bf16x4
typedef __attribute__((ext_vector_type(4))) float f4;
typedef __attribute__((ext_vector_type(2))) unsigned int u2;

typedef const __attribute__((address_space(1))) unsigned int guint_t;
typedef __attribute__((address_space(3))) unsigned int luint_t;

__device__ __forceinline__ short8 pack8(const float* v) {
    __hip_bfloat16 h[8];
    #pragma unroll
    for (int j = 0; j < 8; ++j) h[j] = __float2bfloat16(v[j]);
    return *(short8*)h;
}

// ---------------------------------------------------------------------------
// Kernel A (MFMA): proj_sw = swizzled(x@W^T + b), projT_sw = d-major transpose
//   with per-row 8B-block XOR swizzle ((d&15)<<3 within each 128B tile-row),
//   q = avgpool2(x)@W^T + b.  Both _sw layouts are consumed by linear
//   global_load_lds DMA + swizzled LDS reads in the fused kernel (T2 rule:
//   swizzle source + read, keep DMA dest linear).
// ---------------------------------------------------------------------------
__global__ __launch_bounds__(256) void projA_kernel(
    const float* __restrict__ x, const float* __restrict__ W,
    const float* __restrict__ bias,
    __hip_bfloat16* __restrict__ proj_sw, __hip_bfloat16* __restrict__ projT_sw,
    __hip_bfloat16* __restrict__ qb, float* __restrict__ qf,
    float* __restrict__ psq, float* __restrict__ qsq)
{
    __shared__ __hip_bfloat16 Wlds[128 * 128];      // 32 KB, XOR-swizzled
    __shared__ __hip_bfloat16 Tt[4][128 * 16];      // 4 KB per-wave transpose tile

    const int tid = threadIdx.x;
    const int lane = tid & 63, w = tid >> 6;
    const int lr = lane & 15, lh = lane >> 4;       // frag row / k-chunk

    #pragma unroll
    for (int k = 0; k < 16; ++k) {
        const int f = k * 1024 + tid * 4;           // flat f32 index
        const int e = f >> 7, col = f & 127;
        f4 v = *(const f4*)&W[f];
        __hip_bfloat16 h[4];
        #pragma unroll
        for (int j = 0; j < 4; ++j) h[j] = __float2bfloat16(v[j]);
        const int byte = e * 256 + (((col * 2)) ^ ((e & 7) << 4));
        *(u2*)((char*)Wlds + byte) = *(u2*)h;
    }
    float bv[8];
    #pragma unroll
    for (int nt = 0; nt < 8; ++nt) bv[nt] = bias[nt * 16 + lr];
    __syncthreads();

    const int tile = blockIdx.x;                    // 768 blocks, 1 tile each
    const int row0 = tile * 64 + w * 16;            // wave's 16 rows
    const bool qmode = tile >= (NB * LL / 64);      // >= 512

    short8 a[4];
    if (!qmode) {
        const float* src = x + (size_t)(row0 + lr) * DD;
        #pragma unroll
        for (int ks = 0; ks < 4; ++ks) {
            float t[8];
            *(f4*)&t[0] = *(const f4*)&src[ks * 32 + lh * 8];
            *(f4*)&t[4] = *(const f4*)&src[ks * 32 + lh * 8 + 4];
            a[ks] = pack8(t);
        }
    } else {
        const int gq = row0 - NB * LL + lr;         // global q row
        const int b = gq >> 11, l = gq & 2047;
        const float* s0 = x + ((size_t)b * LL + 2 * l) * DD;
        #pragma unroll
        for (int ks = 0; ks < 4; ++ks) {
            float t[8];
            f4 u0 = *(const f4*)&s0[ks * 32 + lh * 8];
            f4 u1 = *(const f4*)&s0[ks * 32 + lh * 8 + 4];
            f4 v0 = *(const f4*)&s0[DD + ks * 32 + lh * 8];
            f4 v1 = *(const f4*)&s0[DD + ks * 32 + lh * 8 + 4];
            *(f4*)&t[0] = (u0 + v0) * 0.5f;
            *(f4*)&t[4] = (u1 + v1) * 0.5f;
            a[ks] = pack8(t);
        }
    }

    f4 acc[8] = {};
    #pragma unroll
    for (int nt = 0; nt < 8; ++nt) {
        const int e = nt * 16 + lr;
        #pragma unroll
        for (int ks = 0; ks < 4; ++ks) {
            const int byte = e * 256 + ((ks * 64 + lh * 16) ^ ((lr & 7) << 4));
            short8 bk = *(const short8*)((char*)Wlds + byte);
            acc[nt] = __builtin_amdgcn_mfma_f32_16x16x32_bf16(a[ks], bk, acc[nt], 0, 0, 0);
        }
    }

    __hip_bfloat16 h[8][4];
    f4 rn = {0.f, 0.f, 0.f, 0.f};
    #pragma unroll
    for (int nt = 0; nt < 8; ++nt)
        #pragma unroll
        for (int r = 0; r < 4; ++r) {
            float v = acc[nt][r] + bv[nt];
            acc[nt][r] = v;
            h[nt][r] = __float2bfloat16(v);
            float vb = __bfloat162float(h[nt][r]);
            rn[r] += vb * vb;
        }
    #pragma unroll
    for (int m = 1; m < 16; m <<= 1) {
        #pragma unroll
        for (int r = 0; r < 4; ++r) rn[r] += __shfl_xor(rn[r], m);
    }

    if (!qmode) {
        const int gr = row0;
        // swizzled proj write: byte-in-row = (2d) ^ ((row&7)<<4)
        #pragma unroll
        for (int nt = 0; nt < 8; ++nt)
            #pragma unroll
            for (int r = 0; r < 4; ++r) {
                const int row = gr + lh * 4 + r;
                const int byte = (nt * 32 + lr * 2) ^ (((lh * 4 + r) & 7) << 4);
                *(__hip_bfloat16*)((char*)proj_sw + (size_t)row * 256 + byte) = h[nt][r];
            }
        if (lr == 0) *(f4*)&psq[gr + lh * 4] = rn;
        #pragma unroll
        for (int nt = 0; nt < 8; ++nt) {
            __hip_bfloat16 p[4] = {h[nt][0], h[nt][1], h[nt][2], h[nt][3]};
            *(u2*)((char*)&Tt[w][0] + (nt * 16 + lr) * 32 + lh * 8) = *(u2*)p;
        }
        // projT_sw: row d = e (8192 B), tile-rows of 128 B, 8B-block XOR by (e&15)<<3
        const int b = gr >> 12, l0 = gr & 4095;
        #pragma unroll
        for (int i = 0; i < 2; ++i) {
            const int e = lane + i * 64;
            const int sw = (e & 15) << 3;
            char* rowbase = (char*)projT_sw + ((size_t)(b * DD + e)) * (LL * 2)
                          + (size_t)(l0 & ~63) * 2;
            const int ob = (l0 & 63) * 2;           // 16 elems -> 4 x 8B chunks
            #pragma unroll
            for (int c = 0; c < 4; ++c) {
                u2 chunk = *(u2*)((char*)&Tt[w][e * 16] + c * 8);
                *(u2*)(rowbase + ((ob + c * 8) ^ sw)) = chunk;
            }
        }
    } else {
        const int gq = row0 - NB * LL;
        #pragma unroll
        for (int nt = 0; nt < 8; ++nt)
            #pragma unroll
            for (int r = 0; r < 4; ++r) {
                const size_t idx = (size_t)(gq + lh * 4 + r) * DD + nt * 16 + lr;
                qb[idx] = h[nt][r];
                qf[idx] = acc[nt][r];
            }
        if (lr == 0) *(f4*)&qsq[gq + lh * 4] = rn;
    }
}

// ---------------------------------------------------------------------------
// Kernel B: fused similarity, 64-key phases, all-DMA staging, counted-vmcnt
//   raw barriers (T3+T4), setprio around MFMA (T5). Per phase per wave:
//   4 DMA issues; s_waitcnt vmcnt(4) (never 0 in-loop); 2 light barriers;
//   32 MFMA. Swapped-GEMM sim math identical to R2-R5 (verified).
// ---------------------------------------------------------------------------
__global__ __launch_bounds__(512, 4) void fused_kernel(
    const __hip_bfloat16* __restrict__ proj_sw, const __hip_bfloat16* __restrict__ projT_sw,
    const __hip_bfloat16* __restrict__ qb, const float* __restrict__ psq,
    const float* __restrict__ qsq,
    float* __restrict__ pp0, float* __restrict__ pp1,
    float* __restrict__ pp2, float* __restrict__ pp3, int keys_per)
{
    __shared__ __hip_bfloat16 pbuf[2][8192];        // 2 x 16 KB proj tile (swizzled rows)
    __shared__ __hip_bfloat16 tbuf[2][8192];        // 2 x 16 KB projT tile (128B rows, swz)
    __shared__ __align__(16) float psbuf[2048];

    const int bid = blockIdx.x;
    const int b = bid & 7;                          // XCD-pinned batch
    const int qt16 = (bid >> 3) & 15;
    const int ks = bid >> 7;                        // key slice
    const int tid = threadIdx.x;
    const int w = tid >> 6, lane = tid & 63;
    const int lr = lane & 15, lh = lane >> 4;

    const int qrow0 = qt16 * 128 + w * 16;          // wave's 16 q rows
    const int key0 = ks * keys_per;
    const int ntiles = keys_per / 64;               // 64-key phases

    const char* psw = (const char*)proj_sw + (size_t)b * LL * 256;
    const char* ptbsw = (const char*)projT_sw + (size_t)b * DD * LL * 2;
    const float* psb = psq + b * LL;

    // psq slice -> LDS (prologue only; NO global reg-loads inside the loop)
    for (int i = tid; i < keys_per; i += 512) psbuf[i] = psb[key0 + i];

    // q fragments (GEMM1 B-operand) + norm
    short8 aq[4];
    const __hip_bfloat16* qbase = qb + ((size_t)b * LQ + qrow0) * DD;
    #pragma unroll
    for (int kss = 0; kss < 4; ++kss)
        aq[kss] = *(const short8*)&qbase[(size_t)lr * DD + kss * 32 + lh * 8];
    const float qn = qsq[b * LQ + qrow0 + lr];

    __syncthreads();                                // psbuf visible; drains prologue vmem

    // stage phase t into buffer buf: 4 DMA per wave (2 pbuf + 2 tbuf)
    auto stage = [&](int t, int buf) {
        const size_t kb = (size_t)(key0 + t * 64);
        #pragma unroll
        for (int j = 0; j < 2; ++j)
            __builtin_amdgcn_global_load_lds(
                (guint_t*)(psw + kb * 256 + (w * 2 + j) * 1024 + lane * 16),
                (luint_t*)&pbuf[buf][(w * 2 + j) * 512 + lane * 8], 16, 0, 0);
        #pragma unroll
        for (int j = 0; j < 2; ++j) {
            const int row = w * 16 + j * 8 + (lane >> 3);
            __builtin_amdgcn_global_load_lds(
                (guint_t*)(ptbsw + (size_t)row * (LL * 2) + kb * 2 + (lane & 7) * 16),
                (luint_t*)&tbuf[buf][(w * 16 + j * 8) * 64 + lane * 8], 16, 0, 0);
        }
    };

    stage(0, 0);
    stage(1, 1);                                    // depth-1 prefetch: 8 outstanding

    f4 oc[8] = {};                                  // [dt]
    int p = 0;

    for (int t = 0; t < ntiles; ++t) {
        // counted wait: phase t's 4 DMAs done; phase t+1's 4 stay in flight
        if (t + 1 < ntiles) asm volatile("s_waitcnt vmcnt(4)" ::: "memory");
        else                asm volatile("s_waitcnt vmcnt(0)" ::: "memory");
        asm volatile("s_barrier" ::: "memory");     // B1: all waves' t-data visible

        #pragma unroll
        for (int sub = 0; sub < 2; ++sub) {
            // ---- GEMM1 (swapped): S^T[key][q] from pbuf ----
            f4 s[2] = {};
            __builtin_amdgcn_s_setprio(1);
            #pragma unroll
            for (int kss = 0; kss < 4; ++kss) {
                const int off = (kss * 64 + lh * 16) ^ ((lr & 7) << 4);
                short8 ak0 = *(const short8*)((const char*)pbuf[p] + (sub * 32 + lr) * 256 + off);
                short8 ak1 = *(const short8*)((const char*)pbuf[p] + (sub * 32 + 16 + lr) * 256 + off);
                s[0] = __builtin_amdgcn_mfma_f32_16x16x32_bf16(ak0, aq[kss], s[0], 0, 0, 0);
                s[1] = __builtin_amdgcn_mfma_f32_16x16x32_bf16(ak1, aq[kss], s[1], 0, 0, 0);
            }
            __builtin_amdgcn_s_setprio(0);

            // ---- transform: lane holds S^T[t*64+sub*32+16kt+4lh+r][q=lr] ----
            f4 pn0 = *(const f4*)&psbuf[t * 64 + sub * 32 + lh * 4];
            f4 pn1 = *(const f4*)&psbuf[t * 64 + sub * 32 + 16 + lh * 4];
            short8 pa;
            {
                __hip_bfloat16 hh[8];
                #pragma unroll
                for (int r = 0; r < 4; ++r) {
                    float p0 = fmaxf(qn + pn0[r] - 2.0f * s[0][r], 1e-20f);
                    float p1 = fmaxf(qn + pn1[r] - 2.0f * s[1][r], 1e-20f);
                    float d0 = p0 * __frsqrt_rn(p0);
                    float d1 = p1 * __frsqrt_rn(p1);
                    hh[r]     = __float2bfloat16(__expf(-d0));
                    hh[4 + r] = __float2bfloat16(__expf(-d1));
                }
                pa = *(short8*)hh;
            }

            // ---- GEMM2: O += sim @ proj, B-frags from swizzled tbuf ----
            __builtin_amdgcn_s_setprio(1);
            #pragma unroll
            for (int dt = 0; dt < 8; ++dt) {
                const char* rowp = (const char*)tbuf[p] + (dt * 16 + lr) * 128;
                const int sw = lr << 3;
                union { short8 v; short4v h[2]; } u;
                u.h[0] = *(const short4v*)(rowp + ((lh * 8 + sub * 64) ^ sw));
                u.h[1] = *(const short4v*)(rowp + ((lh * 8 + 32 + sub * 64) ^ sw));
                oc[dt] = __builtin_amdgcn_mfma_f32_16x16x32_bf16(pa, u.v, oc[dt], 0, 0, 0);
            }
            __builtin_amdgcn_s_setprio(0);
        }

        asm volatile("s_barrier" ::: "memory");     // B2: all reads of buf[p] done
        if (t + 2 < ntiles) stage(t + 2, p);        // reuse buf[p] for phase t+2
        p ^= 1;
    }

    // ---- partial O store: O[q = qrow0 + lh*4 + r][d = dt*16 + lr] ----
    float* pb = (ks == 0) ? pp0 : (ks == 1) ? pp1 : (ks == 2) ? pp2 : pp3;
    #pragma unroll
    for (int dt = 0; dt < 8; ++dt)
        #pragma unroll
        for (int r = 0; r < 4; ++r)
            pb[((size_t)b * LQ + qrow0 + lh * 4 + r) * DD + dt * 16 + lr] = oc[dt][r];
}

// ---------------------------------------------------------------------------
// Reduce: outk = outv = sum of nsplit partials (p0/p1 alias outk/outv).
// ---------------------------------------------------------------------------
__global__ __launch_bounds__(256) void reduce_kernel(
    const float* __restrict__ p0, const float* __restrict__ p1,
    const float* __restrict__ p2, const float* __restrict__ p3,
    float* __restrict__ outk, float* __restrict__ outv, int nsplit)
{
    const int b = blockIdx.x & 7;
    const size_t j = (size_t)b * (LQ * DD) + ((size_t)(blockIdx.x >> 3) * 256 + threadIdx.x) * 4;
    f4 v = *(const f4*)&p0[j] + *(const f4*)&p1[j];
    if (nsplit == 4) v += *(const f4*)&p2[j] + *(const f4*)&p3[j];
    *(f4*)&outk[j] = v;
    *(f4*)&outv[j] = v;
}

extern "C" void kernel_launch(void* const* d_in, const int* in_sizes, int n_in,
                              void* d_out, int out_size, void* d_ws, size_t ws_size,
                              hipStream_t stream) {
    const float* x = (const float*)d_in[0];
    const float* W = (const float*)d_in[1];
    const float* bias = (const float*)d_in[2];

    float* out = (float*)d_out;
    const size_t NQ = (size_t)NB * LQ * DD;
    float* qf = out;            // output 0: q
    float* outk = out + NQ;     // output 1: k
    float* outv = out + 2 * NQ; // output 2: v

    char* ws = (char*)d_ws;
    __hip_bfloat16* proj  = (__hip_bfloat16*)ws;                          // 8 MB (swizzled)
    __hip_bfloat16* projT = (__hip_bfloat16*)(ws + 8u * 1024 * 1024);     // 8 MB (swizzled)
    __hip_bfloat16* qb    = (__hip_bfloat16*)(ws + 16u * 1024 * 1024);    // 4 MB
    float* psq            = (float*)(ws + 20u * 1024 * 1024);             // 128 KB
    float* qsq            = (float*)(ws + 20u * 1024 * 1024 + 256u * 1024); // 64 KB
    float* pw2            = (float*)(ws + 24u * 1024 * 1024);             // 8 MB partial
    float* pw3            = (float*)(ws + 32u * 1024 * 1024);             // 8 MB partial

    const int nsplit = (ws_size >= (40ull << 20)) ? 4 : 2;
    const int keys_per = LL / nsplit;

    hipLaunchKernelGGL(projA_kernel, dim3((NB * LL + NB * LQ) / 64), dim3(256), 0, stream,
                       x, W, bias, proj, projT, qb, qf, psq, qsq);
    hipLaunchKernelGGL(fused_kernel, dim3(128 * nsplit), dim3(512), 0, stream,
                       proj, projT, qb, psq, qsq, outk, outv, pw2, pw3, keys_per);
    hipLaunchKernelGGL(reduce_kernel, dim3(2048), dim3(256), 0, stream,
                       outk, outv, pw2, pw3, outk, outv, nsplit);
}

// Round 9
// 77.779 us; speedup vs baseline: 2.6550x; 1.0124x over previous
//
#include <hip/hip_runtime.h>
#include <hip/hip_bf16.h>
#include <stdint.h>

#define NB 8
#define LL 4096
#define LQ 2048
#define DD 128

typedef __attribute__((ext_vector_type(8))) short short8;   // bf16x8 MFMA frag
typedef __attribute__((ext_vector_type(4))) short short4v;  // bf16x4
typedef __attribute__((ext_vector_type(4))) float f4;
typedef __attribute__((ext_vector_type(2))) unsigned int u2;

typedef const __attribute__((address_space(1))) unsigned int guint_t;
typedef __attribute__((address_space(3))) unsigned int luint_t;

__device__ __forceinline__ short8 pack8(const float* v) {
    __hip_bfloat16 h[8];
    #pragma unroll
    for (int j = 0; j < 8; ++j) h[j] = __float2bfloat16(v[j]);
    return *(short8*)h;
}

// ---------------------------------------------------------------------------
// Kernel A (MFMA): proj_sw = swizzled(-2 * (x@W^T + b))  [GEMM1 A operand;
//   the -2 prescale lets the fused kernel's MFMA emit `power` directly],
//   projT_sw = unscaled d-major transpose (swizzled), q = avgpool2(x)@W^T+b.
//   psq/qsq computed from the UNSCALED bf16-rounded values (consistency).
// ---------------------------------------------------------------------------
__global__ __launch_bounds__(256) void projA_kernel(
    const float* __restrict__ x, const float* __restrict__ W,
    const float* __restrict__ bias,
    __hip_bfloat16* __restrict__ proj_sw, __hip_bfloat16* __restrict__ projT_sw,
    __hip_bfloat16* __restrict__ qb, float* __restrict__ qf,
    float* __restrict__ psq, float* __restrict__ qsq)
{
    __shared__ __hip_bfloat16 Wlds[128 * 128];      // 32 KB, XOR-swizzled
    __shared__ __hip_bfloat16 Tt[4][128 * 16];      // 4 KB per-wave transpose tile

    const int tid = threadIdx.x;
    const int lane = tid & 63, w = tid >> 6;
    const int lr = lane & 15, lh = lane >> 4;       // frag row / k-chunk

    #pragma unroll
    for (int k = 0; k < 16; ++k) {
        const int f = k * 1024 + tid * 4;           // flat f32 index
        const int e = f >> 7, col = f & 127;
        f4 v = *(const f4*)&W[f];
        __hip_bfloat16 h[4];
        #pragma unroll
        for (int j = 0; j < 4; ++j) h[j] = __float2bfloat16(v[j]);
        const int byte = e * 256 + (((col * 2)) ^ ((e & 7) << 4));
        *(u2*)((char*)Wlds + byte) = *(u2*)h;
    }
    float bv[8];
    #pragma unroll
    for (int nt = 0; nt < 8; ++nt) bv[nt] = bias[nt * 16 + lr];
    __syncthreads();

    const int tile = blockIdx.x;                    // 768 blocks, 1 tile each
    const int row0 = tile * 64 + w * 16;            // wave's 16 rows
    const bool qmode = tile >= (NB * LL / 64);      // >= 512

    short8 a[4];
    if (!qmode) {
        const float* src = x + (size_t)(row0 + lr) * DD;
        #pragma unroll
        for (int ks = 0; ks < 4; ++ks) {
            float t[8];
            *(f4*)&t[0] = *(const f4*)&src[ks * 32 + lh * 8];
            *(f4*)&t[4] = *(const f4*)&src[ks * 32 + lh * 8 + 4];
            a[ks] = pack8(t);
        }
    } else {
        const int gq = row0 - NB * LL + lr;         // global q row
        const int b = gq >> 11, l = gq & 2047;
        const float* s0 = x + ((size_t)b * LL + 2 * l) * DD;
        #pragma unroll
        for (int ks = 0; ks < 4; ++ks) {
            float t[8];
            f4 u0 = *(const f4*)&s0[ks * 32 + lh * 8];
            f4 u1 = *(const f4*)&s0[ks * 32 + lh * 8 + 4];
            f4 v0 = *(const f4*)&s0[DD + ks * 32 + lh * 8];
            f4 v1 = *(const f4*)&s0[DD + ks * 32 + lh * 8 + 4];
            *(f4*)&t[0] = (u0 + v0) * 0.5f;
            *(f4*)&t[4] = (u1 + v1) * 0.5f;
            a[ks] = pack8(t);
        }
    }

    f4 acc[8] = {};
    #pragma unroll
    for (int nt = 0; nt < 8; ++nt) {
        const int e = nt * 16 + lr;
        #pragma unroll
        for (int ks = 0; ks < 4; ++ks) {
            const int byte = e * 256 + ((ks * 64 + lh * 16) ^ ((lr & 7) << 4));
            short8 bk = *(const short8*)((char*)Wlds + byte);
            acc[nt] = __builtin_amdgcn_mfma_f32_16x16x32_bf16(a[ks], bk, acc[nt], 0, 0, 0);
        }
    }

    __hip_bfloat16 h[8][4];
    f4 rn = {0.f, 0.f, 0.f, 0.f};
    #pragma unroll
    for (int nt = 0; nt < 8; ++nt)
        #pragma unroll
        for (int r = 0; r < 4; ++r) {
            float v = acc[nt][r] + bv[nt];
            acc[nt][r] = v;
            h[nt][r] = __float2bfloat16(v);
            float vb = __bfloat162float(h[nt][r]);
            rn[r] += vb * vb;
        }
    #pragma unroll
    for (int m = 1; m < 16; m <<= 1) {
        #pragma unroll
        for (int r = 0; r < 4; ++r) rn[r] += __shfl_xor(rn[r], m);
    }

    if (!qmode) {
        const int gr = row0;
        // swizzled proj write, PRE-SCALED by -2 (exact): byte = (2d)^((row&7)<<4)
        #pragma unroll
        for (int nt = 0; nt < 8; ++nt)
            #pragma unroll
            for (int r = 0; r < 4; ++r) {
                const int row = gr + lh * 4 + r;
                const int byte = (nt * 32 + lr * 2) ^ (((lh * 4 + r) & 7) << 4);
                *(__hip_bfloat16*)((char*)proj_sw + (size_t)row * 256 + byte) =
                    __float2bfloat16(-2.0f * __bfloat162float(h[nt][r]));
            }
        if (lr == 0) *(f4*)&psq[gr + lh * 4] = rn;
        #pragma unroll
        for (int nt = 0; nt < 8; ++nt) {
            __hip_bfloat16 p[4] = {h[nt][0], h[nt][1], h[nt][2], h[nt][3]};
            *(u2*)((char*)&Tt[w][0] + (nt * 16 + lr) * 32 + lh * 8) = *(u2*)p;
        }
        // projT_sw: row d (8192 B), 128B tile-rows, 8B-block XOR by (d&15)<<3
        const int b = gr >> 12, l0 = gr & 4095;
        #pragma unroll
        for (int i = 0; i < 2; ++i) {
            const int e = lane + i * 64;
            const int sw = (e & 15) << 3;
            char* rowbase = (char*)projT_sw + ((size_t)(b * DD + e)) * (LL * 2)
                          + (size_t)(l0 & ~63) * 2;
            const int ob = (l0 & 63) * 2;           // 16 elems -> 4 x 8B chunks
            #pragma unroll
            for (int c = 0; c < 4; ++c) {
                u2 chunk = *(u2*)((char*)&Tt[w][e * 16] + c * 8);
                *(u2*)(rowbase + ((ob + c * 8) ^ sw)) = chunk;
            }
        }
    } else {
        const int gq = row0 - NB * LL;
        #pragma unroll
        for (int nt = 0; nt < 8; ++nt)
            #pragma unroll
            for (int r = 0; r < 4; ++r) {
                const size_t idx = (size_t)(gq + lh * 4 + r) * DD + nt * 16 + lr;
                qb[idx] = h[nt][r];
                qf[idx] = acc[nt][r];
            }
        if (lr == 0) *(f4*)&qsq[gq + lh * 4] = rn;
    }
}

// ---------------------------------------------------------------------------
// Kernel B: fused similarity. Verified 64-key-phase counted-vmcnt schedule
//   (R6); transform slimmed: C-init = qn+pn with -2-prescaled K so the MFMA
//   emits power directly; single-instr v_sqrt. Pack via the R6-proven
//   local-array + __float2bfloat16 idiom (NOT asm-into-union — that produced
//   undef pa in R7: outputs must stay in (0,1], R7's k hit 936).
// ---------------------------------------------------------------------------
__global__ __launch_bounds__(512, 4) void fused_kernel(
    const __hip_bfloat16* __restrict__ proj_sw, const __hip_bfloat16* __restrict__ projT_sw,
    const __hip_bfloat16* __restrict__ qb, const float* __restrict__ psq,
    const float* __restrict__ qsq,
    float* __restrict__ pp0, float* __restrict__ pp1,
    float* __restrict__ pp2, float* __restrict__ pp3, int keys_per)
{
    __shared__ __hip_bfloat16 pbuf[2][8192];        // 2 x 16 KB proj tile (swizzled rows)
    __shared__ __hip_bfloat16 tbuf[2][8192];        // 2 x 16 KB projT tile (128B rows, swz)
    __shared__ __align__(16) float psbuf[2048];

    const int bid = blockIdx.x;
    const int b = bid & 7;                          // XCD-pinned batch
    const int qt16 = (bid >> 3) & 15;
    const int ks = bid >> 7;                        // key slice
    const int tid = threadIdx.x;
    const int w = tid >> 6, lane = tid & 63;
    const int lr = lane & 15, lh = lane >> 4;

    const int qrow0 = qt16 * 128 + w * 16;          // wave's 16 q rows
    const int key0 = ks * keys_per;
    const int ntiles = keys_per / 64;               // 64-key phases

    const char* psw = (const char*)proj_sw + (size_t)b * LL * 256;
    const char* ptbsw = (const char*)projT_sw + (size_t)b * DD * LL * 2;
    const float* psb = psq + b * LL;

    // psq slice -> LDS (prologue only; NO global reg-loads inside the loop)
    for (int i = tid; i < keys_per; i += 512) psbuf[i] = psb[key0 + i];

    // q fragments (GEMM1 B-operand) + norm
    short8 aq[4];
    const __hip_bfloat16* qbase = qb + ((size_t)b * LQ + qrow0) * DD;
    #pragma unroll
    for (int kss = 0; kss < 4; ++kss)
        aq[kss] = *(const short8*)&qbase[(size_t)lr * DD + kss * 32 + lh * 8];
    const float qn = qsq[b * LQ + qrow0 + lr];

    __syncthreads();                                // psbuf visible; drains prologue vmem

    // staging sources as running pointers (advanced once per stage call)
    const char* sp = psw + (size_t)key0 * 256 + w * 2048;                        // +j*1024
    const char* st = ptbsw + (size_t)(w * 16 + (lane >> 3)) * (LL * 2)
                   + (size_t)key0 * 2 + (lane & 7) * 16;                         // +j*8 rows
    auto stage = [&](int buf) {
        #pragma unroll
        for (int j = 0; j < 2; ++j)
            __builtin_amdgcn_global_load_lds(
                (guint_t*)(sp + j * 1024 + lane * 16),
                (luint_t*)&pbuf[buf][w * 1024 + j * 512 + lane * 8], 16, 0, 0);
        #pragma unroll
        for (int j = 0; j < 2; ++j)
            __builtin_amdgcn_global_load_lds(
                (guint_t*)(st + (size_t)j * 8 * (LL * 2)),
                (luint_t*)&tbuf[buf][(w * 16 + j * 8) * 64 + lane * 8], 16, 0, 0);
        sp += 64 * 256;                             // next 64-key phase
        st += 64 * 2;
    };

    stage(0);
    stage(1);                                       // depth-1 prefetch: 8 outstanding

    f4 oc[8] = {};                                  // [dt]
    int p = 0;

    for (int t = 0; t < ntiles; ++t) {
        // pn prefetch for both subs — psbuf is static after the prologue, so
        // these ds_reads sit off the critical path.
        f4 pn[2][2];
        #pragma unroll
        for (int sub = 0; sub < 2; ++sub) {
            pn[sub][0] = *(const f4*)&psbuf[t * 64 + sub * 32 + lh * 4];
            pn[sub][1] = *(const f4*)&psbuf[t * 64 + sub * 32 + 16 + lh * 4];
        }

        // counted wait: phase t's 4 DMAs done; phase t+1's 4 stay in flight
        if (t + 1 < ntiles) asm volatile("s_waitcnt vmcnt(4)" ::: "memory");
        else                asm volatile("s_waitcnt vmcnt(0)" ::: "memory");
        asm volatile("s_barrier" ::: "memory");     // B1: all waves' t-data visible

        #pragma unroll
        for (int sub = 0; sub < 2; ++sub) {
            // ---- GEMM1 (swapped, -2-prescaled K, C-init = qn+pn -> power) ----
            f4 s0, s1;
            #pragma unroll
            for (int r = 0; r < 4; ++r) {
                s0[r] = qn + pn[sub][0][r];
                s1[r] = qn + pn[sub][1][r];
            }
            __builtin_amdgcn_s_setprio(1);
            #pragma unroll
            for (int kss = 0; kss < 4; ++kss) {
                const int off = (kss * 64 + lh * 16) ^ ((lr & 7) << 4);
                short8 ak0 = *(const short8*)((const char*)pbuf[p] + (sub * 32 + lr) * 256 + off);
                short8 ak1 = *(const short8*)((const char*)pbuf[p] + (sub * 32 + 16 + lr) * 256 + off);
                s0 = __builtin_amdgcn_mfma_f32_16x16x32_bf16(ak0, aq[kss], s0, 0, 0, 0);
                s1 = __builtin_amdgcn_mfma_f32_16x16x32_bf16(ak1, aq[kss], s1, 0, 0, 0);
            }
            __builtin_amdgcn_s_setprio(0);

            // ---- transform: power -> exp(-sqrt(max(power,0))), in (0,1] ----
            alignas(16) __hip_bfloat16 hh[8];
            #pragma unroll
            for (int r = 0; r < 4; ++r) {
                float d0 = __builtin_amdgcn_sqrtf(fmaxf(s0[r], 0.0f));
                float d1 = __builtin_amdgcn_sqrtf(fmaxf(s1[r], 0.0f));
                hh[r]     = __float2bfloat16(__expf(-d0));
                hh[4 + r] = __float2bfloat16(__expf(-d1));
            }
            const short8 pa = *(short8*)hh;

            // ---- GEMM2: O += sim @ proj, B-frags from swizzled tbuf ----
            __builtin_amdgcn_s_setprio(1);
            #pragma unroll
            for (int dt = 0; dt < 8; ++dt) {
                const char* rowp = (const char*)tbuf[p] + (dt * 16 + lr) * 128;
                const int sw = lr << 3;
                union { short8 v; short4v h[2]; } u;
                u.h[0] = *(const short4v*)(rowp + ((lh * 8 + sub * 64) ^ sw));
                u.h[1] = *(const short4v*)(rowp + ((lh * 8 + 32 + sub * 64) ^ sw));
                oc[dt] = __builtin_amdgcn_mfma_f32_16x16x32_bf16(pa, u.v, oc[dt], 0, 0, 0);
            }
            __builtin_amdgcn_s_setprio(0);
        }

        asm volatile("s_barrier" ::: "memory");     // B2: all reads of buf[p] done
        if (t + 2 < ntiles) stage(p);               // reuse buf[p] for phase t+2
        p ^= 1;
    }

    // ---- partial O store: O[q = qrow0 + lh*4 + r][d = dt*16 + lr] ----
    float* pb = (ks == 0) ? pp0 : (ks == 1) ? pp1 : (ks == 2) ? pp2 : pp3;
    #pragma unroll
    for (int dt = 0; dt < 8; ++dt)
        #pragma unroll
        for (int r = 0; r < 4; ++r)
            pb[((size_t)b * LQ + qrow0 + lh * 4 + r) * DD + dt * 16 + lr] = oc[dt][r];
}

// ---------------------------------------------------------------------------
// Reduce: outk = outv = sum of nsplit partials (p0/p1 alias outk/outv).
// ---------------------------------------------------------------------------
__global__ __launch_bounds__(256) void reduce_kernel(
    const float* __restrict__ p0, const float* __restrict__ p1,
    const float* __restrict__ p2, const float* __restrict__ p3,
    float* __restrict__ outk, float* __restrict__ outv, int nsplit)
{
    const int b = blockIdx.x & 7;
    const size_t j = (size_t)b * (LQ * DD) + ((size_t)(blockIdx.x >> 3) * 256 + threadIdx.x) * 4;
    f4 v = *(const f4*)&p0[j] + *(const f4*)&p1[j];
    if (nsplit == 4) v += *(const f4*)&p2[j] + *(const f4*)&p3[j];
    *(f4*)&outk[j] = v;
    *(f4*)&outv[j] = v;
}

extern "C" void kernel_launch(void* const* d_in, const int* in_sizes, int n_in,
                              void* d_out, int out_size, void* d_ws, size_t ws_size,
                              hipStream_t stream) {
    const float* x = (const float*)d_in[0];
    const float* W = (const float*)d_in[1];
    const float* bias = (const float*)d_in[2];

    float* out = (float*)d_out;
    const size_t NQ = (size_t)NB * LQ * DD;
    float* qf = out;            // output 0: q
    float* outk = out + NQ;     // output 1: k
    float* outv = out + 2 * NQ; // output 2: v

    char* ws = (char*)d_ws;
    __hip_bfloat16* proj  = (__hip_bfloat16*)ws;                          // 8 MB (swizzled, -2x)
    __hip_bfloat16* projT = (__hip_bfloat16*)(ws + 8u * 1024 * 1024);     // 8 MB (swizzled)
    __hip_bfloat16* qb    = (__hip_bfloat16*)(ws + 16u * 1024 * 1024);    // 4 MB
    float* psq            = (float*)(ws + 20u * 1024 * 1024);             // 128 KB
    float* qsq            = (float*)(ws + 20u * 1024 * 1024 + 256u * 1024); // 64 KB
    float* pw2            = (float*)(ws + 24u * 1024 * 1024);             // 8 MB partial
    float* pw3            = (float*)(ws + 32u * 1024 * 1024);             // 8 MB partial

    const int nsplit = (ws_size >= (40ull << 20)) ? 4 : 2;
    const int keys_per = LL / nsplit;

    hipLaunchKernelGGL(projA_kernel, dim3((NB * LL + NB * LQ) / 64), dim3(256), 0, stream,
                       x, W, bias, proj, projT, qb, qf, psq, qsq);
    hipLaunchKernelGGL(fused_kernel, dim3(128 * nsplit), dim3(512), 0, stream,
                       proj, projT, qb, psq, qsq, outk, outv, pw2, pw3, keys_per);
    hipLaunchKernelGGL(reduce_kernel, dim3(2048), dim3(256), 0, stream,
                       outk, outv, pw2, pw3, outk, outv, nsplit);
}